// Round 9
// baseline (272.944 us; speedup 1.0000x reference)
//
#include <hip/hip_runtime.h>
#include <stdint.h>

// Problem constants
#define PP 8
#define FIN 1024
#define FOUT 1024
#define MROWS 8192
#define ROWSTRIDE 8192
#define OROWSTRIDE 8192

// Tile: 256x256, BK=64, 512 threads = 8 waves as 2(m) x 4(n); wave = 128x64
#define NKT 16

typedef float fx4 __attribute__((ext_vector_type(4)));
typedef short sv8 __attribute__((ext_vector_type(8)));
typedef short sv4 __attribute__((ext_vector_type(4)));

union BCvt4 { sv4 s; __bf16 b[4]; };

__device__ __forceinline__ unsigned short bfbits(float f) {
    union { __bf16 b; unsigned short u; } c; c.b = (__bf16)f; return c.u;
}

// ---------------------------------------------------------------------------
// Swizzled image format (A and B): row*128 + ((kg*16) ^ ((row&7)<<4)), kg=k/8
// ---------------------------------------------------------------------------

// Prepass 1 (verified r5-r8): W [P][K][N] fp32 -> Wt 16 KB tiles (p,nt128,kt)
__global__ __launch_bounds__(256) void wtrans(const float* __restrict__ w,
                                              unsigned short* __restrict__ wt) {
    __shared__ unsigned short L[64][132];
    const int bid = blockIdx.x;              // 1024
    const int p  = bid >> 7;
    const int nt = (bid >> 4) & 7;
    const int kt = bid & 15;
    const int k0 = kt * 64, n0 = nt * 128;
    const int t = threadIdx.x;

    const int nf = t & 31, kl = t >> 5;
#pragma unroll
    for (int rr = 0; rr < 8; ++rr) {
        const int k = rr * 8 + kl;
        fx4 v = *(const fx4*)(w + (size_t)p * (FIN*FOUT) + (size_t)(k0 + k) * FOUT + n0 + nf * 4);
        L[k][nf*4+0] = bfbits(v[0]); L[k][nf*4+1] = bfbits(v[1]);
        L[k][nf*4+2] = bfbits(v[2]); L[k][nf*4+3] = bfbits(v[3]);
    }
    __syncthreads();

    unsigned short* tile = wt + (size_t)bid * 8192;
    const int n = t & 127, khalf = t >> 7;
#pragma unroll
    for (int rr = 0; rr < 4; ++rr) {
        const int kg = khalf * 4 + rr;
        union { sv8 s; unsigned short us[8]; } u;
#pragma unroll
        for (int e = 0; e < 8; ++e) u.us[e] = L[kg * 8 + e][n];
        const int byte_ = n * 128 + ((kg * 16) ^ ((n & 7) << 4));
        *(sv8*)((char*)tile + byte_) = u.s;
    }
}

// Prepass 2 (verified r7-r8): x fp32 -> xt 32 KB tiles (p, mt256, kt)
__global__ __launch_bounds__(256) void xcvt(const float* __restrict__ x,
                                            unsigned short* __restrict__ xt,
                                            int m_base, int MT) {
    const int bid = blockIdx.x;          // 8 * MT * 4
    const int p   = bid & 7;
    const int q   = bid >> 3;
    const int mt  = q >> 2;
    const int seg = q & 3;
    const int w   = threadIdx.x >> 6;
    const int l   = threadIdx.x & 63;

    char* tiles = (char*)xt + (size_t)((p * MT + mt) * 16) * 32768;
    const int ktl = l >> 4;
    const int kg  = (l & 15) >> 1;
    const int e8  = (l & 1) * 8;

#pragma unroll 2
    for (int i = 0; i < 16; ++i) {
        const int r = seg * 64 + w * 16 + i;
        const float* src = x + (size_t)(m_base + mt * 256 + r) * ROWSTRIDE + p * FIN;
        char* rowdst = tiles + r * 128 + ((kg * 16) ^ ((r & 7) << 4)) + e8;
#pragma unroll
        for (int rnd = 0; rnd < 4; ++rnd) {
            fx4 v = *(const fx4*)(src + rnd * 256 + l * 4);
            BCvt4 u;
            u.b[0] = (__bf16)v[0]; u.b[1] = (__bf16)v[1];
            u.b[2] = (__bf16)v[2]; u.b[3] = (__bf16)v[3];
            *(sv4*)(rowdst + (size_t)(rnd * 4 + ktl) * 32768) = u.s;
        }
    }
}

// ---------------------------------------------------------------------------
// 256x256 GEMM, fine 4-phase-per-K-tile interleave (m201 port):
// A tri-buf (stage t+2 @ p2/p3), B dbuf (stage t+1 @ p0/p1), vmcnt(4)/tile.
// ---------------------------------------------------------------------------
#define STR2(x) #x
#define VMC(N) asm volatile("s_waitcnt vmcnt(" STR2(N) ")" ::: "memory")
#define MEMF asm volatile("" ::: "memory")
#define BARX do { MEMF; __builtin_amdgcn_s_barrier(); MEMF; } while (0)
#define LGK0 do { asm volatile("s_waitcnt lgkmcnt(0)" ::: "memory");           \
                  __builtin_amdgcn_sched_barrier(0); } while (0)

// A half h of tile skt -> As + h*16KB : 2 x global_load_lds (512thr x 16B)
#define GLA1(skt, As, h) do {                                                  \
    MEMF;                                                                      \
    const char* s_ = apanel + (size_t)(skt) * 32768 + (h) * 16384 + tid * 16;  \
    char* d_ = (As) + (h) * 16384 + tid * 16;                                  \
    _Pragma("unroll")                                                          \
    for (int c_ = 0; c_ < 2; ++c_)                                             \
        __builtin_amdgcn_global_load_lds(                                      \
            (const __attribute__((address_space(1))) void*)(s_ + c_ * 8192),   \
            (__attribute__((address_space(3))) void*)(d_ + c_ * 8192), 16, 0, 0); \
    MEMF;                                                                      \
} while (0)

// B half h (n-cols h*128..) of tile skt -> Bs + h*16KB : 2 gloads
#define GLB1(skt, Bs, h) do {                                                  \
    MEMF;                                                                      \
    const char* s_ = bpan + (size_t)((h) * 16 + (skt)) * 16384 + tid * 16;     \
    char* d_ = (Bs) + (h) * 16384 + tid * 16;                                  \
    _Pragma("unroll")                                                          \
    for (int c_ = 0; c_ < 2; ++c_)                                             \
        __builtin_amdgcn_global_load_lds(                                      \
            (const __attribute__((address_space(1))) void*)(s_ + c_ * 8192),   \
            (__attribute__((address_space(3))) void*)(d_ + c_ * 8192), 16, 0, 0); \
    MEMF;                                                                      \
} while (0)

// A frags: wave rows wm*128 + mh*64 + fi*16; 8 x ds_read_b128
#define RDA(Ac, mh) do {                                                       \
    _Pragma("unroll")                                                          \
    for (int fi_ = 0; fi_ < 4; ++fi_) {                                        \
        const int row_ = wm * 128 + (mh) * 64 + fi_ * 16 + (lane & 15);        \
        const char* bp_ = (Ac) + row_ * 128;                                   \
        const int sw_ = (row_ & 7) << 4;                                       \
        _Pragma("unroll")                                                      \
        for (int ks_ = 0; ks_ < 2; ++ks_)                                      \
            af[fi_][ks_] = *(const sv8*)(bp_ + ((ks_ * 64 + (lane >> 4) * 16) ^ sw_)); \
    }                                                                          \
} while (0)

// B frags: rows wn*64 + nh*32 + j*16 of the 256-row image; 4 reads
#define RDB(Bc, nh, dst) do {                                                  \
    _Pragma("unroll")                                                          \
    for (int j_ = 0; j_ < 2; ++j_) {                                           \
        const int row_ = wn * 64 + (nh) * 32 + j_ * 16 + (lane & 15);          \
        const char* bp_ = (Bc) + row_ * 128;                                   \
        const int sw_ = (row_ & 7) << 4;                                       \
        _Pragma("unroll")                                                      \
        for (int ks_ = 0; ks_ < 2; ++ks_)                                      \
            dst[j_][ks_] = *(const sv8*)(bp_ + ((ks_ * 64 + (lane >> 4) * 16) ^ sw_)); \
    }                                                                          \
} while (0)

#define MQ(mh, nh, bfr) do {                                                   \
    __builtin_amdgcn_s_setprio(1);                                             \
    _Pragma("unroll")                                                          \
    for (int fi_ = 0; fi_ < 4; ++fi_)                                          \
        _Pragma("unroll")                                                      \
        for (int j_ = 0; j_ < 2; ++j_)                                         \
            _Pragma("unroll")                                                  \
            for (int ks_ = 0; ks_ < 2; ++ks_)                                  \
                acc[(mh)*4+fi_][(nh)*2+j_] = __builtin_amdgcn_mfma_f32_16x16x32_bf16( \
                    af[fi_][ks_], bfr[j_][ks_], acc[(mh)*4+fi_][(nh)*2+j_], 0, 0, 0); \
    __builtin_amdgcn_s_setprio(0);                                             \
} while (0)

// Per-wave vmcnt ledger: entry = 4 outstanding (A(t+1)).
//  p0 +2 (B(t+1)h0), p1 +2 (B(t+1)h1), p2 +2 (A(t+2)h0), p3 +2 (A(t+2)h1)
//  -> 12; VMC(4) retires A(t+1)+B(t+1), leaves A(t+2). Invariant restored.
// ENDW: 2 = vmcnt(4), 1 = vmcnt(0) (t=14), 0 = none (t=15)
#define TILEF(Ar, Br, Bs, As, t, STB, STA, ENDW) do {                          \
    /* phase 0: quadrant (0,0) */                                              \
    RDA((Ar), 0); RDB((Br), 0, bf0);                                           \
    if (STB) GLB1((t) + 1, (Bs), 0);                                           \
    BARX; LGK0; MQ(0, 0, bf0); BARX;                                           \
    /* phase 1: quadrant (0,1) */                                              \
    RDB((Br), 1, bf1);                                                         \
    if (STB) GLB1((t) + 1, (Bs), 1);                                           \
    BARX; LGK0; MQ(0, 1, bf1); BARX;                                           \
    /* phase 2: quadrant (1,1) */                                              \
    RDA((Ar), 1);                                                              \
    if (STA) GLA1((t) + 2, (As), 0);                                           \
    BARX; LGK0; MQ(1, 1, bf1); BARX;                                           \
    /* phase 3: quadrant (1,0) */                                              \
    if (STA) GLA1((t) + 2, (As), 1);                                           \
    if ((ENDW) == 2) { VMC(4); BARX; }                                         \
    else if ((ENDW) == 1) { VMC(0); BARX; }                                    \
    MQ(1, 0, bf0);                                                             \
    if ((ENDW) != 0) BARX;                                                     \
} while (0)

__global__ __launch_bounds__(512, 1)
void pd_gemm(const unsigned short* __restrict__ xt, const unsigned short* __restrict__ wtb,
             const float* __restrict__ bias, float* __restrict__ out,
             int m_base, int MT) {
    __shared__ __align__(16) char A0[32768];
    __shared__ __align__(16) char A1[32768];
    __shared__ __align__(16) char A2[32768];
    __shared__ __align__(16) char B0[32768];
    __shared__ __align__(16) char B1[32768];   // 160 KB exactly

    const int tid = threadIdx.x;
    const int lane = tid & 63;
    const int wv = tid >> 6;            // 8 waves: 2(m) x 4(n); wave = 128x64
    const int wm = wv >> 2, wn = wv & 3;

    const int bid = blockIdx.x;
    const int p   = bid & 7;            // p == XCD
    const int q   = bid >> 3;
    const int nt4 = q & 3;
    const int mt  = q >> 2;
    const int n0  = nt4 * 256;

    const char* apanel = (const char*)xt  + (size_t)((p * MT + mt) * 16) * 32768;
    const char* bpan   = (const char*)wtb + (size_t)(p * 8 + nt4 * 2) * 16 * 16384;

    fx4 acc[8][4];
#pragma unroll
    for (int i = 0; i < 8; ++i)
#pragma unroll
        for (int j = 0; j < 4; ++j) acc[i][j] = (fx4)0.0f;

    sv8 af[4][2], bf0[2][2], bf1[2][2];

    // Prologue: A(0)->A0, B(0)->B0, A(1)->A1 (12 loads); vmcnt(4) leaves A(1).
    GLA1(0, A0, 0); GLA1(0, A0, 1);
    GLB1(0, B0, 0); GLB1(0, B0, 1);
    GLA1(1, A1, 0); GLA1(1, A1, 1);
    VMC(4);
    BARX;

    // Pattern (period 6 over A%3, B&1):
    //  t≡0: read A0,B0; B(t+1)->B1; A(t+2)->A2
    //  t≡1: A1,B1; ->B0; ->A0      t≡2: A2,B0; ->B1; ->A1
    //  t≡3: A0,B1; ->B0; ->A2      t≡4: A1,B0; ->B1; ->A0
    //  t≡5: A2,B1; ->B0; ->A1
#pragma unroll 1
    for (int tb = 0; tb <= 6; tb += 6) {
        TILEF(A0, B0, B1, A2, tb + 0, 1, 1, 2);
        TILEF(A1, B1, B0, A0, tb + 1, 1, 1, 2);
        TILEF(A2, B0, B1, A1, tb + 2, 1, 1, 2);
        TILEF(A0, B1, B0, A2, tb + 3, 1, 1, 2);
        TILEF(A1, B0, B1, A0, tb + 4, 1, 1, 2);
        TILEF(A2, B1, B0, A1, tb + 5, 1, 1, 2);
    }
    TILEF(A0, B0, B1, A2, 12, 1, 1, 2);   // t=12: B13->B1, A14->A2
    TILEF(A1, B1, B0, A0, 13, 1, 1, 2);   // t=13: B14->B0, A15->A0
    TILEF(A2, B0, B1, A1, 14, 1, 0, 1);   // t=14: B15->B1; vmcnt(0)
    TILEF(A0, B1, B0, A1, 15, 0, 0, 0);   // t=15: no staging

    // Epilogue: C/D map col = lane&15, row = (lane>>4)*4 + j (verified)
    const float* bs = bias + p * FOUT;
#pragma unroll
    for (int nf = 0; nf < 4; ++nf) {
        const int col = n0 + wn * 64 + nf * 16 + (lane & 15);
        const float bv = bs[col];
#pragma unroll
        for (int mf = 0; mf < 8; ++mf) {
            const int row = m_base + mt * 256 + wm * 128 + mf * 16 + (lane >> 4) * 4;
            float* o = out + (size_t)row * OROWSTRIDE + p * FOUT + col;
#pragma unroll
            for (int j = 0; j < 4; ++j)
                o[j * OROWSTRIDE] = acc[mf][nf][j] + bv;
        }
    }
}

// Fallback if d_ws too small: correct but slow (fp32 exact).
__global__ __launch_bounds__(256) void pd_naive(const float* __restrict__ x,
                                                const float* __restrict__ w,
                                                const float* __restrict__ bias,
                                                float* __restrict__ out) {
    const long long total = (long long)MROWS * PP * FOUT;
    for (long long idx = blockIdx.x * 256LL + threadIdx.x; idx < total;
         idx += (long long)gridDim.x * 256) {
        const int n = (int)(idx & 1023);
        const int p = (int)((idx >> 10) & 7);
        const long long m = idx >> 13;
        const float* xr = x + m * ROWSTRIDE + p * FIN;
        const float* wc = w + (size_t)p * (FIN*FOUT) + n;
        float s = bias[p * FOUT + n];
        for (int k = 0; k < FIN; ++k) s += xr[k] * wc[(size_t)k * FOUT];
        out[idx] = s;
    }
}

extern "C" void kernel_launch(void* const* d_in, const int* in_sizes, int n_in,
                              void* d_out, int out_size, void* d_ws, size_t ws_size,
                              hipStream_t stream) {
    const float* x    = (const float*)d_in[0];
    const float* w    = (const float*)d_in[1];
    const float* bias = (const float*)d_in[2];
    float* out = (float*)d_out;

    const size_t WT_BYTES = (size_t)PP * FIN * FOUT * 2;          // 16.8 MB
    const size_t XT_FULL  = (size_t)MROWS * PP * FIN * 2;         // 134.2 MB

    int nch = 1;
    while (nch <= 32 && WT_BYTES + XT_FULL / nch > ws_size) nch <<= 1;
    if (nch > 32) {
        pd_naive<<<dim3(2048), dim3(256), 0, stream>>>(x, w, bias, out);
        return;
    }

    unsigned short* wt = (unsigned short*)d_ws;
    unsigned short* xt = (unsigned short*)((char*)d_ws + WT_BYTES);
    const int Mc = MROWS / nch;
    const int MT = Mc / 256;

    wtrans<<<dim3(1024), dim3(256), 0, stream>>>(w, wt);
    for (int c = 0; c < nch; ++c) {
        const int m_base = c * Mc;
        xcvt<<<dim3(8 * MT * 4), dim3(256), 0, stream>>>(x, xt, m_base, MT);
        pd_gemm<<<dim3(8 * MT * 4), dim3(512), 0, stream>>>(xt, wt, bias, out, m_base, MT);
    }
}